// Round 3
// baseline (258.201 us; speedup 1.0000x reference)
//
#include <hip/hip_runtime.h>

// Fused MHA: qkv[4,2048,1024] f32 -> out f32, all GEMMs in bf16 MFMA.
// R9 = R8 resubmit (container infra failure, no measurement) with one
// hardening: mfma_k16 now uses __builtin_amdgcn_mfma_f32_16x16x16bf16_1k
// unconditionally (stable since gfx90a; instruction present in gfx950 ISA)
// instead of a __has_builtin branch that could pick a wrong-signature
// builtin.
//
// flash v6 — P never touches LDS. QK^T acc layout (col=q=lane&15,
// kv=quad*4+r) IS the A-fragment layout of mfma_f32_16x16x16_bf16
// (k=quad*4+e), so PV runs as 2x K=16 MFMA steps per kq with P cast
// in-register. Deletes sP (16KB), its 8-cy/store write conflicts (R7:
// residual 2^23 conflicts = exactly the sP writes), and the serializing
// P-write->lgkm->P-read chain. setprio REVERTED (R7: cost ~4.5us, VGPR
// 120->100 = lost load-ahead ILP; 4-wave lockstep regime, m190).
// GEMMs/prep unchanged from R6.

typedef __bf16 bf16;
typedef __bf16 bf16x4 __attribute__((ext_vector_type(4)));
typedef __bf16 bf16x8 __attribute__((ext_vector_type(8)));
typedef float f32x4 __attribute__((ext_vector_type(4)));
typedef short short4v __attribute__((ext_vector_type(4)));

typedef const __attribute__((address_space(1))) void* gas1p;
typedef __attribute__((address_space(3))) void* las3p;
#define GLD16(g, l) __builtin_amdgcn_global_load_lds((gas1p)(g), (las3p)(l), 16, 0, 0)

#if __has_builtin(__builtin_amdgcn_exp2f)
#define EXP2(x) __builtin_amdgcn_exp2f(x)
#else
#define EXP2(x) exp2f(x)
#endif

__device__ __forceinline__ f32x4 mfma16(bf16x8 a, bf16x8 b, f32x4 c) {
  return __builtin_amdgcn_mfma_f32_16x16x32_bf16(a, b, c, 0, 0, 0);
}

// K=16 variant: A/B are 4 bf16 (2 VGPR), k = quad*4 + e. Use the legacy
// _1k builtin (short4 operands) — stable lowering to v_mfma_f32_16x16x16_bf16.
__device__ __forceinline__ f32x4 mfma_k16(bf16x4 a, bf16x4 b, f32x4 c) {
  return __builtin_amdgcn_mfma_f32_16x16x16bf16_1k(
      __builtin_bit_cast(short4v, a), __builtin_bit_cast(short4v, b), c, 0, 0, 0);
}

// ---------------- prep: cast qkv -> bf16, transpose+cast W_in, W_out ----------------
// blocks 0..8191: cast; 8192..11263: W_in transpose (96x32 tiles); 11264..12287: W_out (32x32)
__global__ void prep_kernel(const float* __restrict__ qkv, bf16* __restrict__ Xb,
                            const float* __restrict__ W_in, bf16* __restrict__ WtIn,
                            const float* __restrict__ W_out, bf16* __restrict__ WtOut) {
  __shared__ float tile[32][33];
  int blk = blockIdx.x, tid = threadIdx.x;
  if (blk < 8192) {
    int i = (blk * 256 + tid) * 4;
    float4 v = *(const float4*)(qkv + i);
    bf16x4 o;
    o[0] = (bf16)v.x; o[1] = (bf16)v.y; o[2] = (bf16)v.z; o[3] = (bf16)v.w;
    *(bf16x4*)(Xb + i) = o;
    return;
  }
  const float* in; bf16* out; int R, C, c0, r0;
  if (blk < 11264) {
    int t = blk - 8192; in = W_in; out = WtIn; R = 1024; C = 3072;
    c0 = (t % 96) * 32; r0 = (t / 96) * 32;
  } else {
    int t = blk - 11264; in = W_out; out = WtOut; R = 1024; C = 1024;
    c0 = (t % 32) * 32; r0 = (t / 32) * 32;
  }
  int tx = tid & 31, ty = tid >> 5;
#pragma unroll
  for (int i = 0; i < 4; ++i)
    tile[ty + i * 8][tx] = in[(size_t)(r0 + ty + i * 8) * C + c0 + tx];
  __syncthreads();
#pragma unroll
  for (int i = 0; i < 4; ++i)
    out[(size_t)(c0 + ty + i * 8) * R + r0 + tx] = (bf16)tile[tx][ty + i * 8];
}

// ======== shared dbuf-GEMM machinery: 128x128 tile, BK=64, K=1024 ========
__device__ __forceinline__ void stage_tile(const bf16* __restrict__ src, size_t rstride,
                                           int kt, char* dst, int tid) {
#pragma unroll
  for (int i = 0; i < 4; ++i) {
    int chunk = i * 256 + tid;
    int row = chunk >> 3;
    int cs = (chunk & 7) ^ (row & 7);
    GLD16(src + (size_t)row * rstride + kt + cs * 8, dst + chunk * 16);
  }
}

__device__ __forceinline__ void gemm_step(
    const bf16* __restrict__ A, const bf16* __restrict__ B, int m0, int n0,
    const char* ca, const char* cb, char* na, char* nb, int ktn, bool pref,
    int tid, int lane, int quad, int wm, int wn, f32x4 (&acc)[4][4]) {
  if (pref) {
    stage_tile(A + (size_t)m0 * 1024, 1024, ktn, na, tid);
    stage_tile(B + (size_t)n0 * 1024, 1024, ktn, nb, tid);
  }
#pragma unroll
  for (int ks = 0; ks < 2; ++ks) {
    bf16x8 af[4], bfr[4];
#pragma unroll
    for (int t = 0; t < 4; ++t) {
      int ra = wm + t * 16 + (lane & 15);
      af[t] = *(const bf16x8*)(ca + ra * 128 + ((ks * 4 + quad) ^ (ra & 7)) * 16);
      int rb = wn + t * 16 + (lane & 15);
      bfr[t] = *(const bf16x8*)(cb + rb * 128 + ((ks * 4 + quad) ^ (rb & 7)) * 16);
    }
#pragma unroll
    for (int mt = 0; mt < 4; ++mt)
#pragma unroll
      for (int nt = 0; nt < 4; ++nt)
        acc[mt][nt] = mfma16(af[mt], bfr[nt], acc[mt][nt]);
  }
  __syncthreads();
}

// ---------------- GEMM1: A[8192,1024] @ Bt[3072,1024]^T + bias -> Q,K,Vt (bf16) ----------------
// 1536 blocks flat. XCD partition: xcd=id&7 owns m-tiles xcd*8..xcd*8+7 (A slab
// 2MB L2-resident); n streamed, 8 m-tiles back-to-back per n (B panel reuse).
__global__ __launch_bounds__(256, 2) void gemm1_kernel(
    const bf16* __restrict__ A, const bf16* __restrict__ Bt, const float* __restrict__ bias,
    bf16* __restrict__ Qo, bf16* __restrict__ Ko, bf16* __restrict__ Vo) {
  __shared__ __align__(16) char sA[2][128 * 64 * 2];
  __shared__ __align__(16) char sB[2][128 * 64 * 2];
  const int tid = threadIdx.x, lane = tid & 63, quad = lane >> 4;
  const int wave = tid >> 6;
  const int id = blockIdx.x, xcd = id & 7, local = id >> 3;
  const int m0 = (xcd * 8 + (local & 7)) * 128, n0 = (local >> 3) * 128;
  const int wm = (wave >> 1) * 64, wn = (wave & 1) * 64;
  f32x4 acc[4][4] = {};

  stage_tile(A + (size_t)m0 * 1024, 1024, 0, sA[0], tid);
  stage_tile(Bt + (size_t)n0 * 1024, 1024, 0, sB[0], tid);
  __syncthreads();
  for (int it = 0; it < 16; it += 2) {
    gemm_step(A, Bt, m0, n0, sA[0], sB[0], sA[1], sB[1], (it + 1) * 64, true,
              tid, lane, quad, wm, wn, acc);
    gemm_step(A, Bt, m0, n0, sA[1], sB[1], sA[0], sB[0], (it + 2) * 64, it + 2 < 16,
              tid, lane, quad, wm, wn, acc);
  }

  const int region = n0 >> 10;  // 0=Q, 1=K, 2=V
#pragma unroll
  for (int nt = 0; nt < 4; ++nt) {
    int n = n0 + wn + nt * 16 + (lane & 15);
    float bv = bias[n];
    int ncol = n & 1023;
    int h = ncol >> 6, d = ncol & 63;
#pragma unroll
    for (int mt = 0; mt < 4; ++mt) {
      int gm = m0 + wm + mt * 16 + quad * 4;
      int bb = gm >> 11, s = gm & 2047;
      if (region == 2) {
        bf16x4 pk;
#pragma unroll
        for (int r = 0; r < 4; ++r) pk[r] = (bf16)(acc[mt][nt][r] + bv);
        *(bf16x4*)(Vo + ((size_t)((bb * 16 + h) * 64 + d)) * 2048 + s) = pk;
      } else {
        bf16* dst = (region == 0) ? Qo : Ko;
        // Q scale: 1/sqrt(64) * log2(e)  (softmax done in base-2)
        float scl = (region == 0) ? 0.18033688f : 1.0f;
#pragma unroll
        for (int r = 0; r < 4; ++r)
          dst[((size_t)((bb * 16 + h) * 2048) + s + r) * 64 + d] =
              (bf16)((acc[mt][nt][r] + bv) * scl);
      }
    }
  }
}

// ---------------- flash attention v6: P in registers, PV via K=16 MFMA ----------------
__global__ __launch_bounds__(256, 2) void flash_kernel(
    const bf16* __restrict__ Q, const bf16* __restrict__ K, const bf16* __restrict__ Vt,
    bf16* __restrict__ ctx) {
  const int n = blockIdx.x;
  const int bh = (n & 7) * 8 + (n >> 6);   // XCD swizzle: 8 heads share an XCD L2
  const int qt = (n >> 3) & 7;
  const int b = bh >> 4, h = bh & 15;
  const int tid = threadIdx.x, lane = tid & 63, wave = tid >> 6, quad = lane >> 4;

  __shared__ __align__(16) char sK[2][128 * 64 * 2];  // K dbuf, 2x16KB
  __shared__ __align__(16) char sV[2][64 * 128 * 2];  // V dbuf [d][kv], 2x16KB

  const size_t hb = (size_t)bh * 2048 * 64;
  const int q0 = qt * 256;

#pragma unroll
  for (int i = 0; i < 8; ++i) {
    int chunk = i * 256 + tid;
    int row = chunk >> 3;
    int cs = (chunk & 7) ^ (row & 7);
    char* dst = (i < 4) ? (sK[0] + chunk * 16) : (sK[1] + (chunk - 1024) * 16);
    GLD16(Q + hb + (size_t)(q0 + row) * 64 + cs * 8, dst);
  }
  __syncthreads();
  bf16x8 qf[4][2];
#pragma unroll
  for (int j = 0; j < 4; ++j)
#pragma unroll
    for (int ksd = 0; ksd < 2; ++ksd) {
      int row = wave * 64 + j * 16 + (lane & 15);
      const char* src = sK[row >> 7];
      int r128 = row & 127;
      qf[j][ksd] = *(const bf16x8*)(src + r128 * 128 + ((ksd * 4 + quad) ^ (r128 & 7)) * 16);
    }
  __syncthreads();

#pragma unroll
  for (int i = 0; i < 4; ++i) {
    int chunk = i * 256 + tid;
    int row = chunk >> 3;
    int cs = (chunk & 7) ^ (row & 7);
    GLD16(K + hb + (size_t)row * 64 + cs * 8, sK[0] + chunk * 16);
    int vrow = chunk >> 4;
    int vcs = (chunk & 15) ^ (vrow & 7);
    GLD16(Vt + hb + (size_t)vrow * 2048 + vcs * 8, sV[0] + chunk * 16);
  }
  __syncthreads();

  f32x4 ctxa[4][4] = {};
  float l[4] = {0.f, 0.f, 0.f, 0.f};

  for (int it = 0; it < 16; ++it) {
    const int kv0 = it * 128;
    if (it < 15) {
      char* nk = sK[(it + 1) & 1];
      char* nv = sV[(it + 1) & 1];
#pragma unroll
      for (int i = 0; i < 4; ++i) {
        int chunk = i * 256 + tid;
        int row = chunk >> 3;
        int cs = (chunk & 7) ^ (row & 7);
        GLD16(K + hb + (size_t)(kv0 + 128 + row) * 64 + cs * 8, nk + chunk * 16);
        int vrow = chunk >> 4;
        int vcs = (chunk & 15) ^ (vrow & 7);
        GLD16(Vt + hb + (size_t)vrow * 2048 + kv0 + 128 + vcs * 8, nv + chunk * 16);
      }
    }
    const char* cb = sK[it & 1];
    const char* vb = sV[it & 1];

#pragma unroll
    for (int kq = 0; kq < 4; ++kq) {
      // ---- QK^T: st[ii][j], col q = j*16+(lane&15), row kv = kq*32+ii*16+quad*4+r
      f32x4 st[2][4] = {};
#pragma unroll
      for (int ksd = 0; ksd < 2; ++ksd) {
        bf16x8 kf[2];
#pragma unroll
        for (int ii = 0; ii < 2; ++ii) {
          int row = kq * 32 + ii * 16 + (lane & 15);
          kf[ii] = *(const bf16x8*)(cb + row * 128 + ((ksd * 4 + quad) ^ (row & 7)) * 16);
        }
#pragma unroll
        for (int ii = 0; ii < 2; ++ii)
#pragma unroll
          for (int j = 0; j < 4; ++j)
            st[ii][j] = mfma16(kf[ii], qf[j][ksd], st[ii][j]);
      }
      // ---- softmax (base-2, no max-sub) + in-register bf16 pack.
      // pa[ii][j] elements r=0..3 are kv = quad*4+r of K16-block (kq,ii):
      // exactly the A-fragment k-order of mfma_f32_16x16x16_bf16.
      bf16x4 pa[2][4];
#pragma unroll
      for (int ii = 0; ii < 2; ++ii)
#pragma unroll
        for (int j = 0; j < 4; ++j) {
          bf16x4 pk;
#pragma unroll
          for (int r = 0; r < 4; ++r) {
            float p = EXP2(st[ii][j][r]);
            l[j] += p;
            pk[r] = (bf16)p;
          }
          pa[ii][j] = pk;
        }
      // ---- V B-fragments: lane needs kv = kq*32+ii*16+quad*4..+3 of row d.
      // sV physical chunk = logical ^ (row&7); our 8B lies at byte (quad&1)*8.
      bf16x4 vf4[2][4];
#pragma unroll
      for (int ii = 0; ii < 2; ++ii)
#pragma unroll
        for (int nd = 0; nd < 4; ++nd) {
          int row = nd * 16 + (lane & 15);
          int lc = kq * 4 + ii * 2 + (quad >> 1);
          vf4[ii][nd] = *(const bf16x4*)(vb + row * 256 + ((lc ^ (row & 7)) * 16) +
                                         (quad & 1) * 8);
        }
      // ---- PV: two K=16 steps, P straight from registers.
#pragma unroll
      for (int ii = 0; ii < 2; ++ii)
#pragma unroll
        for (int mt = 0; mt < 4; ++mt)
#pragma unroll
          for (int nd = 0; nd < 4; ++nd)
            ctxa[mt][nd] = mfma_k16(pa[ii][mt], vf4[ii][nd], ctxa[mt][nd]);
    }
    __syncthreads();
  }

#pragma unroll
  for (int j = 0; j < 4; ++j) {
    l[j] += __shfl_xor(l[j], 16);
    l[j] += __shfl_xor(l[j], 32);
  }
#pragma unroll
  for (int mt = 0; mt < 4; ++mt)
#pragma unroll
    for (int r = 0; r < 4; ++r) {
      float lsh = __shfl(l[mt], quad * 4 + r);
      float rl = __builtin_amdgcn_rcpf(lsh);
      int srow = q0 + wave * 64 + mt * 16 + quad * 4 + r;
#pragma unroll
      for (int nd = 0; nd < 4; ++nd) {
        int col = h * 64 + nd * 16 + (lane & 15);
        ctx[((size_t)(b * 2048 + srow)) * 1024 + col] = (bf16)(ctxa[mt][nd][r] * rl);
      }
    }
}

// ---------------- GEMM2: ctx[8192,1024] @ Bt[1024,1024]^T + b_out -> f32 out ----------------
// 512 blocks flat. XCD partition: xcd=id&7 owns m-tiles xcd*8..+7; per-XCD
// footprint A 2MB + B 2MB = 4MB (fits L2).
__global__ __launch_bounds__(256, 2) void gemm2_kernel(
    const bf16* __restrict__ A, const bf16* __restrict__ Bt, const float* __restrict__ bias,
    float* __restrict__ Out) {
  __shared__ __align__(16) char sA[2][128 * 64 * 2];
  __shared__ __align__(16) char sB[2][128 * 64 * 2];
  const int tid = threadIdx.x, lane = tid & 63, quad = lane >> 4;
  const int wave = tid >> 6;
  const int id = blockIdx.x, xcd = id & 7, local = id >> 3;
  const int m0 = (xcd * 8 + (local & 7)) * 128, n0 = (local >> 3) * 128;
  const int wm = (wave >> 1) * 64, wn = (wave & 1) * 64;
  f32x4 acc[4][4] = {};

  stage_tile(A + (size_t)m0 * 1024, 1024, 0, sA[0], tid);
  stage_tile(Bt + (size_t)n0 * 1024, 1024, 0, sB[0], tid);
  __syncthreads();
  for (int it = 0; it < 16; it += 2) {
    gemm_step(A, Bt, m0, n0, sA[0], sB[0], sA[1], sB[1], (it + 1) * 64, true,
              tid, lane, quad, wm, wn, acc);
    gemm_step(A, Bt, m0, n0, sA[1], sB[1], sA[0], sB[0], (it + 2) * 64, it + 2 < 16,
              tid, lane, quad, wm, wn, acc);
  }

#pragma unroll
  for (int nt = 0; nt < 4; ++nt) {
    int n = n0 + wn + nt * 16 + (lane & 15);
    float bv = bias[n];
#pragma unroll
    for (int mt = 0; mt < 4; ++mt) {
      int gm = m0 + wm + mt * 16 + quad * 4;
#pragma unroll
      for (int r = 0; r < 4; ++r)
        Out[(size_t)(gm + r) * 1024 + n] = acc[mt][nt][r] + bv;
    }
  }
}

extern "C" void kernel_launch(void* const* d_in, const int* in_sizes, int n_in,
                              void* d_out, int out_size, void* d_ws, size_t ws_size,
                              hipStream_t stream) {
  const float* qkv   = (const float*)d_in[0];
  const float* W_in  = (const float*)d_in[1];
  const float* b_in  = (const float*)d_in[2];
  const float* W_out = (const float*)d_in[3];
  const float* b_out = (const float*)d_in[4];
  float* out = (float*)d_out;

  bf16* Xb    = (bf16*)d_ws;
  bf16* WtIn  = Xb + 8388608;
  bf16* WtOut = WtIn + 3145728;
  bf16* Qb    = WtOut + 1048576;
  bf16* Kb    = Qb + 8388608;
  bf16* Vtb   = Kb + 8388608;
  bf16* Ctx   = Xb;

  prep_kernel<<<12288, 256, 0, stream>>>(qkv, Xb, W_in, WtIn, W_out, WtOut);
  gemm1_kernel<<<1536, 256, 0, stream>>>(Xb, WtIn, b_in, Qb, Kb, Vtb);
  flash_kernel<<<512, 256, 0, stream>>>(Qb, Kb, Vtb, Ctx);
  gemm2_kernel<<<512, 256, 0, stream>>>(Ctx, WtOut, b_out, out);
}

// Round 4
// 245.073 us; speedup vs baseline: 1.0536x; 1.0536x over previous
//
#include <hip/hip_runtime.h>

// Fused MHA: qkv[4,2048,1024] f32 -> out f32, all GEMMs in bf16 MFMA.
// R10: flash v7 — K=32 PV via sP restored (R9 measured K=16 MFMA at the
// SAME cycles as K=32 = half rate: PV MFMA time 27.6->42.8us). sP now uses
// a provably balanced 8B-granular layout: write slot s=(ii*4+quad)^(q&6)
// (q&6 even => logical 16B pairs stay adjacent), read b128 at chunk
// quad^((q>>1)&3). Per-parity XOR set {0,2,4,6} puts exactly 4 lanes per
// bank-pair on writes and 8 lanes per 4-bank group on reads = LDS wire
// speed, zero conflict (R6's 1.678e7 conflicts = sP write 4-way + read
// 4-way; R7's partial fix left cross-quad 4-way writes). No setprio (R7:
// -4.5us in this 4-wave lockstep regime). GEMMs/prep unchanged from R6.

typedef __bf16 bf16;
typedef __bf16 bf16x4 __attribute__((ext_vector_type(4)));
typedef __bf16 bf16x8 __attribute__((ext_vector_type(8)));
typedef float f32x4 __attribute__((ext_vector_type(4)));

typedef const __attribute__((address_space(1))) void* gas1p;
typedef __attribute__((address_space(3))) void* las3p;
#define GLD16(g, l) __builtin_amdgcn_global_load_lds((gas1p)(g), (las3p)(l), 16, 0, 0)

#if __has_builtin(__builtin_amdgcn_exp2f)
#define EXP2(x) __builtin_amdgcn_exp2f(x)
#else
#define EXP2(x) exp2f(x)
#endif

__device__ __forceinline__ f32x4 mfma16(bf16x8 a, bf16x8 b, f32x4 c) {
  return __builtin_amdgcn_mfma_f32_16x16x32_bf16(a, b, c, 0, 0, 0);
}

// ---------------- prep: cast qkv -> bf16, transpose+cast W_in, W_out ----------------
// blocks 0..8191: cast; 8192..11263: W_in transpose (96x32 tiles); 11264..12287: W_out (32x32)
__global__ void prep_kernel(const float* __restrict__ qkv, bf16* __restrict__ Xb,
                            const float* __restrict__ W_in, bf16* __restrict__ WtIn,
                            const float* __restrict__ W_out, bf16* __restrict__ WtOut) {
  __shared__ float tile[32][33];
  int blk = blockIdx.x, tid = threadIdx.x;
  if (blk < 8192) {
    int i = (blk * 256 + tid) * 4;
    float4 v = *(const float4*)(qkv + i);
    bf16x4 o;
    o[0] = (bf16)v.x; o[1] = (bf16)v.y; o[2] = (bf16)v.z; o[3] = (bf16)v.w;
    *(bf16x4*)(Xb + i) = o;
    return;
  }
  const float* in; bf16* out; int R, C, c0, r0;
  if (blk < 11264) {
    int t = blk - 8192; in = W_in; out = WtIn; R = 1024; C = 3072;
    c0 = (t % 96) * 32; r0 = (t / 96) * 32;
  } else {
    int t = blk - 11264; in = W_out; out = WtOut; R = 1024; C = 1024;
    c0 = (t % 32) * 32; r0 = (t / 32) * 32;
  }
  int tx = tid & 31, ty = tid >> 5;
#pragma unroll
  for (int i = 0; i < 4; ++i)
    tile[ty + i * 8][tx] = in[(size_t)(r0 + ty + i * 8) * C + c0 + tx];
  __syncthreads();
#pragma unroll
  for (int i = 0; i < 4; ++i)
    out[(size_t)(c0 + ty + i * 8) * R + r0 + tx] = (bf16)tile[tx][ty + i * 8];
}

// ======== shared dbuf-GEMM machinery: 128x128 tile, BK=64, K=1024 ========
__device__ __forceinline__ void stage_tile(const bf16* __restrict__ src, size_t rstride,
                                           int kt, char* dst, int tid) {
#pragma unroll
  for (int i = 0; i < 4; ++i) {
    int chunk = i * 256 + tid;
    int row = chunk >> 3;
    int cs = (chunk & 7) ^ (row & 7);
    GLD16(src + (size_t)row * rstride + kt + cs * 8, dst + chunk * 16);
  }
}

__device__ __forceinline__ void gemm_step(
    const bf16* __restrict__ A, const bf16* __restrict__ B, int m0, int n0,
    const char* ca, const char* cb, char* na, char* nb, int ktn, bool pref,
    int tid, int lane, int quad, int wm, int wn, f32x4 (&acc)[4][4]) {
  if (pref) {
    stage_tile(A + (size_t)m0 * 1024, 1024, ktn, na, tid);
    stage_tile(B + (size_t)n0 * 1024, 1024, ktn, nb, tid);
  }
#pragma unroll
  for (int ks = 0; ks < 2; ++ks) {
    bf16x8 af[4], bfr[4];
#pragma unroll
    for (int t = 0; t < 4; ++t) {
      int ra = wm + t * 16 + (lane & 15);
      af[t] = *(const bf16x8*)(ca + ra * 128 + ((ks * 4 + quad) ^ (ra & 7)) * 16);
      int rb = wn + t * 16 + (lane & 15);
      bfr[t] = *(const bf16x8*)(cb + rb * 128 + ((ks * 4 + quad) ^ (rb & 7)) * 16);
    }
#pragma unroll
    for (int mt = 0; mt < 4; ++mt)
#pragma unroll
      for (int nt = 0; nt < 4; ++nt)
        acc[mt][nt] = mfma16(af[mt], bfr[nt], acc[mt][nt]);
  }
  __syncthreads();
}

// ---------------- GEMM1: A[8192,1024] @ Bt[3072,1024]^T + bias -> Q,K,Vt (bf16) ----------------
// 1536 blocks flat. XCD partition: xcd=id&7 owns m-tiles xcd*8..xcd*8+7 (A slab
// 2MB L2-resident); n streamed, 8 m-tiles back-to-back per n (B panel reuse).
__global__ __launch_bounds__(256, 2) void gemm1_kernel(
    const bf16* __restrict__ A, const bf16* __restrict__ Bt, const float* __restrict__ bias,
    bf16* __restrict__ Qo, bf16* __restrict__ Ko, bf16* __restrict__ Vo) {
  __shared__ __align__(16) char sA[2][128 * 64 * 2];
  __shared__ __align__(16) char sB[2][128 * 64 * 2];
  const int tid = threadIdx.x, lane = tid & 63, quad = lane >> 4;
  const int wave = tid >> 6;
  const int id = blockIdx.x, xcd = id & 7, local = id >> 3;
  const int m0 = (xcd * 8 + (local & 7)) * 128, n0 = (local >> 3) * 128;
  const int wm = (wave >> 1) * 64, wn = (wave & 1) * 64;
  f32x4 acc[4][4] = {};

  stage_tile(A + (size_t)m0 * 1024, 1024, 0, sA[0], tid);
  stage_tile(Bt + (size_t)n0 * 1024, 1024, 0, sB[0], tid);
  __syncthreads();
  for (int it = 0; it < 16; it += 2) {
    gemm_step(A, Bt, m0, n0, sA[0], sB[0], sA[1], sB[1], (it + 1) * 64, true,
              tid, lane, quad, wm, wn, acc);
    gemm_step(A, Bt, m0, n0, sA[1], sB[1], sA[0], sB[0], (it + 2) * 64, it + 2 < 16,
              tid, lane, quad, wm, wn, acc);
  }

  const int region = n0 >> 10;  // 0=Q, 1=K, 2=V
#pragma unroll
  for (int nt = 0; nt < 4; ++nt) {
    int n = n0 + wn + nt * 16 + (lane & 15);
    float bv = bias[n];
    int ncol = n & 1023;
    int h = ncol >> 6, d = ncol & 63;
#pragma unroll
    for (int mt = 0; mt < 4; ++mt) {
      int gm = m0 + wm + mt * 16 + quad * 4;
      int bb = gm >> 11, s = gm & 2047;
      if (region == 2) {
        bf16x4 pk;
#pragma unroll
        for (int r = 0; r < 4; ++r) pk[r] = (bf16)(acc[mt][nt][r] + bv);
        *(bf16x4*)(Vo + ((size_t)((bb * 16 + h) * 64 + d)) * 2048 + s) = pk;
      } else {
        bf16* dst = (region == 0) ? Qo : Ko;
        // Q scale: 1/sqrt(64) * log2(e)  (softmax done in base-2)
        float scl = (region == 0) ? 0.18033688f : 1.0f;
#pragma unroll
        for (int r = 0; r < 4; ++r)
          dst[((size_t)((bb * 16 + h) * 2048) + s + r) * 64 + d] =
              (bf16)((acc[mt][nt][r] + bv) * scl);
      }
    }
  }
}

// ---------------- flash attention v7: K=32 PV, balanced sP ----------------
__global__ __launch_bounds__(256, 2) void flash_kernel(
    const bf16* __restrict__ Q, const bf16* __restrict__ K, const bf16* __restrict__ Vt,
    bf16* __restrict__ ctx) {
  const int n = blockIdx.x;
  const int bh = (n & 7) * 8 + (n >> 6);   // XCD swizzle: 8 heads share an XCD L2
  const int qt = (n >> 3) & 7;
  const int b = bh >> 4, h = bh & 15;
  const int tid = threadIdx.x, lane = tid & 63, wave = tid >> 6, quad = lane >> 4;

  __shared__ __align__(16) char sK[2][128 * 64 * 2];  // K dbuf, 2x16KB
  __shared__ __align__(16) char sV[2][64 * 128 * 2];  // V dbuf [d][kv], 2x16KB
  __shared__ __align__(16) char sP[4][64 * 32 * 2];   // per-wave [64q][32kv] 4KB

  const size_t hb = (size_t)bh * 2048 * 64;
  const int q0 = qt * 256;

#pragma unroll
  for (int i = 0; i < 8; ++i) {
    int chunk = i * 256 + tid;
    int row = chunk >> 3;
    int cs = (chunk & 7) ^ (row & 7);
    char* dst = (i < 4) ? (sK[0] + chunk * 16) : (sK[1] + (chunk - 1024) * 16);
    GLD16(Q + hb + (size_t)(q0 + row) * 64 + cs * 8, dst);
  }
  __syncthreads();
  bf16x8 qf[4][2];
#pragma unroll
  for (int j = 0; j < 4; ++j)
#pragma unroll
    for (int ksd = 0; ksd < 2; ++ksd) {
      int row = wave * 64 + j * 16 + (lane & 15);
      const char* src = sK[row >> 7];
      int r128 = row & 127;
      qf[j][ksd] = *(const bf16x8*)(src + r128 * 128 + ((ksd * 4 + quad) ^ (r128 & 7)) * 16);
    }
  __syncthreads();

#pragma unroll
  for (int i = 0; i < 4; ++i) {
    int chunk = i * 256 + tid;
    int row = chunk >> 3;
    int cs = (chunk & 7) ^ (row & 7);
    GLD16(K + hb + (size_t)row * 64 + cs * 8, sK[0] + chunk * 16);
    int vrow = chunk >> 4;
    int vcs = (chunk & 15) ^ (vrow & 7);
    GLD16(Vt + hb + (size_t)vrow * 2048 + vcs * 8, sV[0] + chunk * 16);
  }
  __syncthreads();

  f32x4 ctxa[4][4] = {};
  float l[4] = {0.f, 0.f, 0.f, 0.f};
  char* pw = sP[wave];

  for (int it = 0; it < 16; ++it) {
    const int kv0 = it * 128;
    if (it < 15) {
      char* nk = sK[(it + 1) & 1];
      char* nv = sV[(it + 1) & 1];
#pragma unroll
      for (int i = 0; i < 4; ++i) {
        int chunk = i * 256 + tid;
        int row = chunk >> 3;
        int cs = (chunk & 7) ^ (row & 7);
        GLD16(K + hb + (size_t)(kv0 + 128 + row) * 64 + cs * 8, nk + chunk * 16);
        int vrow = chunk >> 4;
        int vcs = (chunk & 15) ^ (vrow & 7);
        GLD16(Vt + hb + (size_t)vrow * 2048 + kv0 + 128 + vcs * 8, nv + chunk * 16);
      }
    }
    const char* cb = sK[it & 1];
    const char* vb = sV[it & 1];

#pragma unroll
    for (int kq = 0; kq < 4; ++kq) {
      // ---- QK^T: st[ii][j], col q = j*16+(lane&15), row kv = kq*32+ii*16+quad*4+r
      f32x4 st[2][4] = {};
#pragma unroll
      for (int ksd = 0; ksd < 2; ++ksd) {
        bf16x8 kf[2];
#pragma unroll
        for (int ii = 0; ii < 2; ++ii) {
          int row = kq * 32 + ii * 16 + (lane & 15);
          kf[ii] = *(const bf16x8*)(cb + row * 128 + ((ksd * 4 + quad) ^ (row & 7)) * 16);
        }
#pragma unroll
        for (int ii = 0; ii < 2; ++ii)
#pragma unroll
          for (int j = 0; j < 4; ++j)
            st[ii][j] = mfma16(kf[ii], qf[j][ksd], st[ii][j]);
      }
      // ---- softmax (base-2) + sP write. Lane's 8B covers kv slot
      // s = ii*4+quad of row q. Swizzle s^(q&6): per parity class the XOR
      // set {0,2,4,6} gives exactly 4 lanes per 8B bank-pair = wire speed.
#pragma unroll
      for (int ii = 0; ii < 2; ++ii)
#pragma unroll
        for (int j = 0; j < 4; ++j) {
          f32x4 p;
#pragma unroll
          for (int r = 0; r < 4; ++r) {
            p[r] = EXP2(st[ii][j][r]);
            l[j] += p[r];
          }
          bf16x4 pk;
#pragma unroll
          for (int r = 0; r < 4; ++r) pk[r] = (bf16)p[r];
          int q = j * 16 + (lane & 15);
          int s = (ii * 4 + quad) ^ (q & 6);
          *(bf16x4*)(pw + q * 64 + s * 8) = pk;
        }
      // ---- sP read: logical slots {2quad,2quad+1}; q&6 even keeps them
      // adjacent after swizzle -> single b128 at chunk quad^((q>>1)&3).
      // 8 lanes x 16B per 4-bank group = wire speed, zero conflict.
      bf16x8 pf[4], vf[4];
#pragma unroll
      for (int mt = 0; mt < 4; ++mt) {
        int q = mt * 16 + (lane & 15);
        pf[mt] = *(const bf16x8*)(pw + q * 64 + ((quad ^ ((q >> 1) & 3)) * 16));
      }
#pragma unroll
      for (int nd = 0; nd < 4; ++nd) {
        int row = nd * 16 + (lane & 15);
        vf[nd] = *(const bf16x8*)(vb + row * 256 + (((kq * 4 + quad) ^ (row & 7)) * 16));
      }
#pragma unroll
      for (int mt = 0; mt < 4; ++mt)
#pragma unroll
        for (int nd = 0; nd < 4; ++nd)
          ctxa[mt][nd] = mfma16(pf[mt], vf[nd], ctxa[mt][nd]);
    }
    __syncthreads();
  }

#pragma unroll
  for (int j = 0; j < 4; ++j) {
    l[j] += __shfl_xor(l[j], 16);
    l[j] += __shfl_xor(l[j], 32);
  }
#pragma unroll
  for (int mt = 0; mt < 4; ++mt)
#pragma unroll
    for (int r = 0; r < 4; ++r) {
      float lsh = __shfl(l[mt], quad * 4 + r);
      float rl = __builtin_amdgcn_rcpf(lsh);
      int srow = q0 + wave * 64 + mt * 16 + quad * 4 + r;
#pragma unroll
      for (int nd = 0; nd < 4; ++nd) {
        int col = h * 64 + nd * 16 + (lane & 15);
        ctx[((size_t)(b * 2048 + srow)) * 1024 + col] = (bf16)(ctxa[mt][nd][r] * rl);
      }
    }
}

// ---------------- GEMM2: ctx[8192,1024] @ Bt[1024,1024]^T + b_out -> f32 out ----------------
// 512 blocks flat. XCD partition: xcd=id&7 owns m-tiles xcd*8..+7; per-XCD
// footprint A 2MB + B 2MB = 4MB (fits L2).
__global__ __launch_bounds__(256, 2) void gemm2_kernel(
    const bf16* __restrict__ A, const bf16* __restrict__ Bt, const float* __restrict__ bias,
    float* __restrict__ Out) {
  __shared__ __align__(16) char sA[2][128 * 64 * 2];
  __shared__ __align__(16) char sB[2][128 * 64 * 2];
  const int tid = threadIdx.x, lane = tid & 63, quad = lane >> 4;
  const int wave = tid >> 6;
  const int id = blockIdx.x, xcd = id & 7, local = id >> 3;
  const int m0 = (xcd * 8 + (local & 7)) * 128, n0 = (local >> 3) * 128;
  const int wm = (wave >> 1) * 64, wn = (wave & 1) * 64;
  f32x4 acc[4][4] = {};

  stage_tile(A + (size_t)m0 * 1024, 1024, 0, sA[0], tid);
  stage_tile(Bt + (size_t)n0 * 1024, 1024, 0, sB[0], tid);
  __syncthreads();
  for (int it = 0; it < 16; it += 2) {
    gemm_step(A, Bt, m0, n0, sA[0], sB[0], sA[1], sB[1], (it + 1) * 64, true,
              tid, lane, quad, wm, wn, acc);
    gemm_step(A, Bt, m0, n0, sA[1], sB[1], sA[0], sB[0], (it + 2) * 64, it + 2 < 16,
              tid, lane, quad, wm, wn, acc);
  }

#pragma unroll
  for (int nt = 0; nt < 4; ++nt) {
    int n = n0 + wn + nt * 16 + (lane & 15);
    float bv = bias[n];
#pragma unroll
    for (int mt = 0; mt < 4; ++mt) {
      int gm = m0 + wm + mt * 16 + quad * 4;
#pragma unroll
      for (int r = 0; r < 4; ++r)
        Out[(size_t)(gm + r) * 1024 + n] = acc[mt][nt][r] + bv;
    }
  }
}

extern "C" void kernel_launch(void* const* d_in, const int* in_sizes, int n_in,
                              void* d_out, int out_size, void* d_ws, size_t ws_size,
                              hipStream_t stream) {
  const float* qkv   = (const float*)d_in[0];
  const float* W_in  = (const float*)d_in[1];
  const float* b_in  = (const float*)d_in[2];
  const float* W_out = (const float*)d_in[3];
  const float* b_out = (const float*)d_in[4];
  float* out = (float*)d_out;

  bf16* Xb    = (bf16*)d_ws;
  bf16* WtIn  = Xb + 8388608;
  bf16* WtOut = WtIn + 3145728;
  bf16* Qb    = WtOut + 1048576;
  bf16* Kb    = Qb + 8388608;
  bf16* Vtb   = Kb + 8388608;
  bf16* Ctx   = Xb;

  prep_kernel<<<12288, 256, 0, stream>>>(qkv, Xb, W_in, WtIn, W_out, WtOut);
  gemm1_kernel<<<1536, 256, 0, stream>>>(Xb, WtIn, b_in, Qb, Kb, Vtb);
  flash_kernel<<<512, 256, 0, stream>>>(Qb, Kb, Vtb, Ctx);
  gemm2_kernel<<<512, 256, 0, stream>>>(Ctx, WtOut, b_out, out);
}

// Round 6
// 245.032 us; speedup vs baseline: 1.0537x; 1.0002x over previous
//
#include <hip/hip_runtime.h>

// Fused MHA: qkv[4,2048,1024] f32 -> out f32, all GEMMs in bf16 MFMA.
// R12 = R11 resubmit (GPU acquisition timeout, never measured).
// gemm1/gemm2 K-loop: phase-split + COUNTED vmcnt (T3+T4).
// Each K-step = 2 phases by B row-half: ph0 reads af(all)+bfr(nt 0,1),
// ph1 reads bfr(nt 2,3); af lives in regs across phases. Stage units for
// tile t+1: [A full: 4 gld + B-half0: 2 gld] issued ph0, [B-half1: 2 gld]
// issued ph1. Steady-state waits: vmcnt(2) at ph0 (drains A,B0; leaves B1),
// vmcnt(6) at ph1 (drains B1; leaves next A+B0) — never 0 in the loop
// (m218: counted-vs-drain0 = +38-73%; m248 grouped K=1024: +10..29%).
// FIFO ledger re-audited: 8 outstanding steady-state, row coverage and
// WAR hazards verified. Raw s_barrier + sched_barrier(0) pins; GLD16
// units lane-linear (m104). setprio around MFMA clusters (phase-split
// regime: m218b/m224). Flash v7 unchanged (81.4us, control). prep unchanged.

typedef __bf16 bf16;
typedef __bf16 bf16x4 __attribute__((ext_vector_type(4)));
typedef __bf16 bf16x8 __attribute__((ext_vector_type(8)));
typedef float f32x4 __attribute__((ext_vector_type(4)));

typedef const __attribute__((address_space(1))) void* gas1p;
typedef __attribute__((address_space(3))) void* las3p;
#define GLD16(g, l) __builtin_amdgcn_global_load_lds((gas1p)(g), (las3p)(l), 16, 0, 0)

#if __has_builtin(__builtin_amdgcn_exp2f)
#define EXP2(x) __builtin_amdgcn_exp2f(x)
#else
#define EXP2(x) exp2f(x)
#endif

// counted vmcnt wait; memory clobber keeps all VMEM/DS ops on their side.
#define WAITV(n) asm volatile("s_waitcnt vmcnt(" #n ")" ::: "memory")

__device__ __forceinline__ void barp() {
  __builtin_amdgcn_sched_barrier(0);
  __builtin_amdgcn_s_barrier();
  __builtin_amdgcn_sched_barrier(0);
}

__device__ __forceinline__ f32x4 mfma16(bf16x8 a, bf16x8 b, f32x4 c) {
  return __builtin_amdgcn_mfma_f32_16x16x32_bf16(a, b, c, 0, 0, 0);
}

// ---------------- prep: cast qkv -> bf16, transpose+cast W_in, W_out ----------------
__global__ void prep_kernel(const float* __restrict__ qkv, bf16* __restrict__ Xb,
                            const float* __restrict__ W_in, bf16* __restrict__ WtIn,
                            const float* __restrict__ W_out, bf16* __restrict__ WtOut) {
  __shared__ float tile[32][33];
  int blk = blockIdx.x, tid = threadIdx.x;
  if (blk < 8192) {
    int i = (blk * 256 + tid) * 4;
    float4 v = *(const float4*)(qkv + i);
    bf16x4 o;
    o[0] = (bf16)v.x; o[1] = (bf16)v.y; o[2] = (bf16)v.z; o[3] = (bf16)v.w;
    *(bf16x4*)(Xb + i) = o;
    return;
  }
  const float* in; bf16* out; int R, C, c0, r0;
  if (blk < 11264) {
    int t = blk - 8192; in = W_in; out = WtIn; R = 1024; C = 3072;
    c0 = (t % 96) * 32; r0 = (t / 96) * 32;
  } else {
    int t = blk - 11264; in = W_out; out = WtOut; R = 1024; C = 1024;
    c0 = (t % 32) * 32; r0 = (t / 32) * 32;
  }
  int tx = tid & 31, ty = tid >> 5;
#pragma unroll
  for (int i = 0; i < 4; ++i)
    tile[ty + i * 8][tx] = in[(size_t)(r0 + ty + i * 8) * C + c0 + tx];
  __syncthreads();
#pragma unroll
  for (int i = 0; i < 4; ++i)
    out[(size_t)(c0 + ty + i * 8) * R + r0 + tx] = (bf16)tile[tx][ty + i * 8];
}

// ======== phased-GEMM machinery: 128x128 tile, BK=64, K=1024 ========
// Stage one full matrix tile (128 rows x 64 k) = 4 GLD16/thread, lane-linear.
__device__ __forceinline__ void stage_mat(const bf16* __restrict__ src, int kt,
                                          char* dst, int tid) {
#pragma unroll
  for (int i = 0; i < 4; ++i) {
    int chunk = i * 256 + tid;
    int row = chunk >> 3;
    int cs = (chunk & 7) ^ (row & 7);
    GLD16(src + (size_t)row * 1024 + kt + cs * 8, dst + chunk * 16);
  }
}

// Stage B nt-half b: rows [32b,32b+32) U [64+32b,96+32b) = 2 GLD16/thread,
// each region chunk = const + tid (lane-linear, m104-safe).
__device__ __forceinline__ void stage_bhalf(const bf16* __restrict__ src, int kt,
                                            char* dst, int tid, int b) {
#pragma unroll
  for (int i = 0; i < 2; ++i) {
    int chunk = (i * 64 + b * 32) * 8 + tid;
    int row = chunk >> 3;
    int cs = (chunk & 7) ^ (row & 7);
    GLD16(src + (size_t)row * 1024 + kt + cs * 8, dst + chunk * 16);
  }
}

// Shared phased K-loop. acc[mt][nt] as before.
__device__ __forceinline__ void gemm_core(
    const bf16* __restrict__ Ab, const bf16* __restrict__ Bb,
    char sA[2][128 * 64 * 2], char sB[2][128 * 64 * 2],
    int tid, int lane, int quad, int wm, int wn, f32x4 (&acc)[4][4]) {
  // prologue: tile 0 units in FIFO order A, B0, B1 (8 loads outstanding)
  stage_mat(Ab, 0, sA[0], tid);
  stage_bhalf(Bb, 0, sB[0], tid, 0);
  stage_bhalf(Bb, 0, sB[0], tid, 1);

  for (int t = 0; t < 16; ++t) {
    const int cur = t & 1;
    const int ktn = (t + 1) * 64;
    const char* ca = sA[cur];
    const char* cb = sB[cur];
    char* na = sA[cur ^ 1];
    char* nb = sB[cur ^ 1];

    // ---------- phase 0: needs A(t), B0(t); B1(t) may stay in flight ----
    WAITV(2);
    barp();
    bf16x8 af[4][2], bfr[2][2];
#pragma unroll
    for (int mt = 0; mt < 4; ++mt)
#pragma unroll
      for (int ks = 0; ks < 2; ++ks) {
        int ra = wm + mt * 16 + (lane & 15);
        af[mt][ks] = *(const bf16x8*)(ca + ra * 128 + ((ks * 4 + quad) ^ (ra & 7)) * 16);
      }
#pragma unroll
    for (int j = 0; j < 2; ++j)
#pragma unroll
      for (int ks = 0; ks < 2; ++ks) {
        int rb = wn + j * 16 + (lane & 15);
        bfr[j][ks] = *(const bf16x8*)(cb + rb * 128 + ((ks * 4 + quad) ^ (rb & 7)) * 16);
      }
    if (t < 15) {
      stage_mat(Ab, ktn, na, tid);        // A(t+1): 4 loads
      stage_bhalf(Bb, ktn, nb, tid, 0);   // B0(t+1): 2 loads
    }
    __builtin_amdgcn_s_setprio(1);
#pragma unroll
    for (int ks = 0; ks < 2; ++ks)
#pragma unroll
      for (int mt = 0; mt < 4; ++mt)
#pragma unroll
        for (int j = 0; j < 2; ++j)
          acc[mt][j] = mfma16(af[mt][ks], bfr[j][ks], acc[mt][j]);
    __builtin_amdgcn_s_setprio(0);

    // ---------- phase 1: needs B1(t); A(t+1),B0(t+1) stay in flight -----
    if (t < 15) {
      WAITV(6);
    } else {
      WAITV(0);
    }
    barp();
#pragma unroll
    for (int j = 0; j < 2; ++j)
#pragma unroll
      for (int ks = 0; ks < 2; ++ks) {
        int rb = wn + (2 + j) * 16 + (lane & 15);
        bfr[j][ks] = *(const bf16x8*)(cb + rb * 128 + ((ks * 4 + quad) ^ (rb & 7)) * 16);
      }
    if (t < 15) stage_bhalf(Bb, ktn, nb, tid, 1);  // B1(t+1): 2 loads
    __builtin_amdgcn_s_setprio(1);
#pragma unroll
    for (int ks = 0; ks < 2; ++ks)
#pragma unroll
      for (int mt = 0; mt < 4; ++mt)
#pragma unroll
        for (int j = 0; j < 2; ++j)
          acc[mt][2 + j] = mfma16(af[mt][ks], bfr[j][ks], acc[mt][2 + j]);
    __builtin_amdgcn_s_setprio(0);
  }
}

// ---------------- GEMM1: A[8192,1024] @ Bt[3072,1024]^T + bias -> Q,K,Vt (bf16) ----------------
__global__ __launch_bounds__(256, 2) void gemm1_kernel(
    const bf16* __restrict__ A, const bf16* __restrict__ Bt, const float* __restrict__ bias,
    bf16* __restrict__ Qo, bf16* __restrict__ Ko, bf16* __restrict__ Vo) {
  __shared__ __align__(16) char sA[2][128 * 64 * 2];
  __shared__ __align__(16) char sB[2][128 * 64 * 2];
  const int tid = threadIdx.x, lane = tid & 63, quad = lane >> 4;
  const int wave = tid >> 6;
  const int id = blockIdx.x, xcd = id & 7, local = id >> 3;
  const int m0 = (xcd * 8 + (local & 7)) * 128, n0 = (local >> 3) * 128;
  const int wm = (wave >> 1) * 64, wn = (wave & 1) * 64;
  f32x4 acc[4][4] = {};

  gemm_core(A + (size_t)m0 * 1024, Bt + (size_t)n0 * 1024, sA, sB,
            tid, lane, quad, wm, wn, acc);

  const int region = n0 >> 10;  // 0=Q, 1=K, 2=V
#pragma unroll
  for (int nt = 0; nt < 4; ++nt) {
    int n = n0 + wn + nt * 16 + (lane & 15);
    float bv = bias[n];
    int ncol = n & 1023;
    int h = ncol >> 6, d = ncol & 63;
#pragma unroll
    for (int mt = 0; mt < 4; ++mt) {
      int gm = m0 + wm + mt * 16 + quad * 4;
      int bb = gm >> 11, s = gm & 2047;
      if (region == 2) {
        bf16x4 pk;
#pragma unroll
        for (int r = 0; r < 4; ++r) pk[r] = (bf16)(acc[mt][nt][r] + bv);
        *(bf16x4*)(Vo + ((size_t)((bb * 16 + h) * 64 + d)) * 2048 + s) = pk;
      } else {
        bf16* dst = (region == 0) ? Qo : Ko;
        // Q scale: 1/sqrt(64) * log2(e)  (softmax done in base-2)
        float scl = (region == 0) ? 0.18033688f : 1.0f;
#pragma unroll
        for (int r = 0; r < 4; ++r)
          dst[((size_t)((bb * 16 + h) * 2048) + s + r) * 64 + d] =
              (bf16)((acc[mt][nt][r] + bv) * scl);
      }
    }
  }
}

// ---------------- flash attention v7: K=32 PV, balanced sP (unchanged) ----------------
__global__ __launch_bounds__(256, 2) void flash_kernel(
    const bf16* __restrict__ Q, const bf16* __restrict__ K, const bf16* __restrict__ Vt,
    bf16* __restrict__ ctx) {
  const int n = blockIdx.x;
  const int bh = (n & 7) * 8 + (n >> 6);   // XCD swizzle: 8 heads share an XCD L2
  const int qt = (n >> 3) & 7;
  const int b = bh >> 4, h = bh & 15;
  const int tid = threadIdx.x, lane = tid & 63, wave = tid >> 6, quad = lane >> 4;

  __shared__ __align__(16) char sK[2][128 * 64 * 2];  // K dbuf, 2x16KB
  __shared__ __align__(16) char sV[2][64 * 128 * 2];  // V dbuf [d][kv], 2x16KB
  __shared__ __align__(16) char sP[4][64 * 32 * 2];   // per-wave [64q][32kv] 4KB

  const size_t hb = (size_t)bh * 2048 * 64;
  const int q0 = qt * 256;

#pragma unroll
  for (int i = 0; i < 8; ++i) {
    int chunk = i * 256 + tid;
    int row = chunk >> 3;
    int cs = (chunk & 7) ^ (row & 7);
    char* dst = (i < 4) ? (sK[0] + chunk * 16) : (sK[1] + (chunk - 1024) * 16);
    GLD16(Q + hb + (size_t)(q0 + row) * 64 + cs * 8, dst);
  }
  __syncthreads();
  bf16x8 qf[4][2];
#pragma unroll
  for (int j = 0; j < 4; ++j)
#pragma unroll
    for (int ksd = 0; ksd < 2; ++ksd) {
      int row = wave * 64 + j * 16 + (lane & 15);
      const char* src = sK[row >> 7];
      int r128 = row & 127;
      qf[j][ksd] = *(const bf16x8*)(src + r128 * 128 + ((ksd * 4 + quad) ^ (r128 & 7)) * 16);
    }
  __syncthreads();

#pragma unroll
  for (int i = 0; i < 4; ++i) {
    int chunk = i * 256 + tid;
    int row = chunk >> 3;
    int cs = (chunk & 7) ^ (row & 7);
    GLD16(K + hb + (size_t)row * 64 + cs * 8, sK[0] + chunk * 16);
    int vrow = chunk >> 4;
    int vcs = (chunk & 15) ^ (vrow & 7);
    GLD16(Vt + hb + (size_t)vrow * 2048 + vcs * 8, sV[0] + chunk * 16);
  }
  __syncthreads();

  f32x4 ctxa[4][4] = {};
  float l[4] = {0.f, 0.f, 0.f, 0.f};
  char* pw = sP[wave];

  for (int it = 0; it < 16; ++it) {
    const int kv0 = it * 128;
    if (it < 15) {
      char* nk = sK[(it + 1) & 1];
      char* nv = sV[(it + 1) & 1];
#pragma unroll
      for (int i = 0; i < 4; ++i) {
        int chunk = i * 256 + tid;
        int row = chunk >> 3;
        int cs = (chunk & 7) ^ (row & 7);
        GLD16(K + hb + (size_t)(kv0 + 128 + row) * 64 + cs * 8, nk + chunk * 16);
        int vrow = chunk >> 4;
        int vcs = (chunk & 15) ^ (vrow & 7);
        GLD16(Vt + hb + (size_t)vrow * 2048 + kv0 + 128 + vcs * 8, nv + chunk * 16);
      }
    }
    const char* cb = sK[it & 1];
    const char* vb = sV[it & 1];

#pragma unroll
    for (int kq = 0; kq < 4; ++kq) {
      // ---- QK^T: st[ii][j], col q = j*16+(lane&15), row kv = kq*32+ii*16+quad*4+r
      f32x4 st[2][4] = {};
#pragma unroll
      for (int ksd = 0; ksd < 2; ++ksd) {
        bf16x8 kf[2];
#pragma unroll
        for (int ii = 0; ii < 2; ++ii) {
          int row = kq * 32 + ii * 16 + (lane & 15);
          kf[ii] = *(const bf16x8*)(cb + row * 128 + ((ksd * 4 + quad) ^ (row & 7)) * 16);
        }
#pragma unroll
        for (int ii = 0; ii < 2; ++ii)
#pragma unroll
          for (int j = 0; j < 4; ++j)
            st[ii][j] = mfma16(kf[ii], qf[j][ksd], st[ii][j]);
      }
      // ---- softmax (base-2) + sP write, balanced swizzle s=(ii*4+quad)^(q&6)
#pragma unroll
      for (int ii = 0; ii < 2; ++ii)
#pragma unroll
        for (int j = 0; j < 4; ++j) {
          f32x4 p;
#pragma unroll
          for (int r = 0; r < 4; ++r) {
            p[r] = EXP2(st[ii][j][r]);
            l[j] += p[r];
          }
          bf16x4 pk;
#pragma unroll
          for (int r = 0; r < 4; ++r) pk[r] = (bf16)p[r];
          int q = j * 16 + (lane & 15);
          int s = (ii * 4 + quad) ^ (q & 6);
          *(bf16x4*)(pw + q * 64 + s * 8) = pk;
        }
      bf16x8 pf[4], vf[4];
#pragma unroll
      for (int mt = 0; mt < 4; ++mt) {
        int q = mt * 16 + (lane & 15);
        pf[mt] = *(const bf16x8*)(pw + q * 64 + ((quad ^ ((q >> 1) & 3)) * 16));
      }
#pragma unroll
      for (int nd = 0; nd < 4; ++nd) {
        int row = nd * 16 + (lane & 15);
        vf[nd] = *(const bf16x8*)(vb + row * 256 + (((kq * 4 + quad) ^ (row & 7)) * 16));
      }
#pragma unroll
      for (int mt = 0; mt < 4; ++mt)
#pragma unroll
        for (int nd = 0; nd < 4; ++nd)
          ctxa[mt][nd] = mfma16(pf[mt], vf[nd], ctxa[mt][nd]);
    }
    __syncthreads();
  }

#pragma unroll
  for (int j = 0; j < 4; ++j) {
    l[j] += __shfl_xor(l[j], 16);
    l[j] += __shfl_xor(l[j], 32);
  }
#pragma unroll
  for (int mt = 0; mt < 4; ++mt)
#pragma unroll
    for (int r = 0; r < 4; ++r) {
      float lsh = __shfl(l[mt], quad * 4 + r);
      float rl = __builtin_amdgcn_rcpf(lsh);
      int srow = q0 + wave * 64 + mt * 16 + quad * 4 + r;
#pragma unroll
      for (int nd = 0; nd < 4; ++nd) {
        int col = h * 64 + nd * 16 + (lane & 15);
        ctx[((size_t)(b * 2048 + srow)) * 1024 + col] = (bf16)(ctxa[mt][nd][r] * rl);
      }
    }
}

// ---------------- GEMM2: ctx[8192,1024] @ Bt[1024,1024]^T + b_out -> f32 out ----------------
__global__ __launch_bounds__(256, 2) void gemm2_kernel(
    const bf16* __restrict__ A, const bf16* __restrict__ Bt, const float* __restrict__ bias,
    float* __restrict__ Out) {
  __shared__ __align__(16) char sA[2][128 * 64 * 2];
  __shared__ __align__(16) char sB[2][128 * 64 * 2];
  const int tid = threadIdx.x, lane = tid & 63, quad = lane >> 4;
  const int wave = tid >> 6;
  const int id = blockIdx.x, xcd = id & 7, local = id >> 3;
  const int m0 = (xcd * 8 + (local & 7)) * 128, n0 = (local >> 3) * 128;
  const int wm = (wave >> 1) * 64, wn = (wave & 1) * 64;
  f32x4 acc[4][4] = {};

  gemm_core(A + (size_t)m0 * 1024, Bt + (size_t)n0 * 1024, sA, sB,
            tid, lane, quad, wm, wn, acc);

#pragma unroll
  for (int nt = 0; nt < 4; ++nt) {
    int n = n0 + wn + nt * 16 + (lane & 15);
    float bv = bias[n];
#pragma unroll
    for (int mt = 0; mt < 4; ++mt) {
      int gm = m0 + wm + mt * 16 + quad * 4;
#pragma unroll
      for (int r = 0; r < 4; ++r)
        Out[(size_t)(gm + r) * 1024 + n] = acc[mt][nt][r] + bv;
    }
  }
}

extern "C" void kernel_launch(void* const* d_in, const int* in_sizes, int n_in,
                              void* d_out, int out_size, void* d_ws, size_t ws_size,
                              hipStream_t stream) {
  const float* qkv   = (const float*)d_in[0];
  const float* W_in  = (const float*)d_in[1];
  const float* b_in  = (const float*)d_in[2];
  const float* W_out = (const float*)d_in[3];
  const float* b_out = (const float*)d_in[4];
  float* out = (float*)d_out;

  bf16* Xb    = (bf16*)d_ws;
  bf16* WtIn  = Xb + 8388608;
  bf16* WtOut = WtIn + 3145728;
  bf16* Qb    = WtOut + 1048576;
  bf16* Kb    = Qb + 8388608;
  bf16* Vtb   = Kb + 8388608;
  bf16* Ctx   = Xb;

  prep_kernel<<<12288, 256, 0, stream>>>(qkv, Xb, W_in, WtIn, W_out, WtOut);
  gemm1_kernel<<<1536, 256, 0, stream>>>(Xb, WtIn, b_in, Qb, Kb, Vtb);
  flash_kernel<<<512, 256, 0, stream>>>(Qb, Kb, Vtb, Ctx);
  gemm2_kernel<<<512, 256, 0, stream>>>(Ctx, WtOut, b_out, out);
}